// Round 16
// baseline (52.147 us; speedup 1.0000x reference)
//
#include <hip/hip_runtime.h>

#define NBATCH 2
#define NPTS   16384
#define TPTS   32                      // points per MFMA tile (32x32x16)
#define NTILES (NPTS / TPTS)           // 512
#define JCH    8                       // col-chunks per (dir,n): 2048 cols each
#define NT_PER (NTILES / JCH)          // 64 col-tiles per chunk
#define TG     (NPTS / 256)            // 64 row-groups (block = 4 waves x 64 rows)

typedef float f32x16 __attribute__((ext_vector_type(16)));
typedef short s16x8  __attribute__((ext_vector_type(8)));

__device__ __forceinline__ unsigned short f2bf(float f) {   // RTNE, finite inputs
    unsigned u = __float_as_uint(f);
    u += 0x7FFF + ((u >> 16) & 1);
    return (unsigned short)(u >> 16);
}
__device__ __forceinline__ float bf2f(unsigned short h) {
    return __uint_as_float((unsigned)h << 16);
}

// Inline-asm MFMA: VGPR destination (no ACC-class tax), literal-0 C.
__device__ __forceinline__ f32x16 mfma32(s16x8 a, s16x8 b) {
    f32x16 d;
    asm volatile("v_mfma_f32_32x32x16_bf16 %0, %1, %2, 0"
                 : "=&v"(d) : "v"(a), "v"(b));
    return d;
}
__device__ __forceinline__ void min3f(float& acc, float x, float y) {
    asm("v_min3_f32 %0, %1, %2, %3" : "=v"(acc) : "v"(acc), "v"(x), "v"(y));
}
__device__ __forceinline__ float min3v(float x, float y, float z) {
    float r;
    asm("v_min3_f32 %0, %1, %2, %3" : "=v"(r) : "v"(x), "v"(y), "v"(z));
    return r;
}

// K=16 panels: BOTH clouds in BOTH encodings (R11-proven slot layout).
// A slots: [ah(3) | al(3) | ah(3) | 1 1 | sqa_h sqa_l | 0 0 0]
// B slots: [-2bh(3)| -2bh(3)| -2bl(3)| sqb_h sqb_l | 1 1 | 0 0 0]
// dot = sqa + sqb - 2(ah+al)·bh - 2ah·bl = d^2 + eps, |eps| <~ 1.3e-4 worst.
// Also initializes the mins arrays (fused memset).
__global__ __launch_bounds__(256) void pack_panels(
    const float* __restrict__ c1, const float* __restrict__ c2,
    unsigned short* __restrict__ apan, unsigned short* __restrict__ bpan,
    unsigned int* __restrict__ mins)
{
    int tid = blockIdx.x * 256 + threadIdx.x;   // 2^18 threads
    if (tid < 2 * NBATCH * NPTS) mins[tid] = 0x7F7F7F7Fu;   // fused init

    int lane   = tid & 63;
    int tile   = (tid >> 6) & (NTILES - 1);
    int n      = (tid >> 15) & 1;
    int whichB = (tid >> 16) & 1;
    int wc     = (tid >> 17) & 1;               // which cloud

    const float* src = wc ? c2 : c1;

    int p = tile * TPTS + (lane & 31);
    const float* q = src + ((size_t)n * NPTS + p) * 3;
    float x = q[0], y = q[1], z = q[2];

    unsigned short xh = f2bf(x), yh = f2bf(y), zh = f2bf(z);
    unsigned short xl = f2bf(x - bf2f(xh)), yl = f2bf(y - bf2f(yh)), zl = f2bf(z - bf2f(zh));
    float sq = x * x + y * y + z * z;
    unsigned short sh = f2bf(sq);
    unsigned short sl = f2bf(sq - bf2f(sh));
    const unsigned short one = 0x3F80;

    unsigned short slots[16];
    if (!whichB) {
        slots[0]=xh;  slots[1]=yh;  slots[2]=zh;
        slots[3]=xl;  slots[4]=yl;  slots[5]=zl;
        slots[6]=xh;  slots[7]=yh;  slots[8]=zh;
        slots[9]=one; slots[10]=one;
        slots[11]=sh; slots[12]=sl;
        slots[13]=0;  slots[14]=0;  slots[15]=0;
    } else {
        unsigned short mxh=f2bf(-2.f*bf2f(xh)), myh=f2bf(-2.f*bf2f(yh)), mzh=f2bf(-2.f*bf2f(zh));
        unsigned short mxl=f2bf(-2.f*bf2f(xl)), myl=f2bf(-2.f*bf2f(yl)), mzl=f2bf(-2.f*bf2f(zl));
        slots[0]=mxh; slots[1]=myh; slots[2]=mzh;
        slots[3]=mxh; slots[4]=myh; slots[5]=mzh;
        slots[6]=mxl; slots[7]=myl; slots[8]=mzl;
        slots[9]=sh;  slots[10]=sl;
        slots[11]=one; slots[12]=one;
        slots[13]=0;  slots[14]=0;  slots[15]=0;
    }

    int j0 = (lane >> 5) * 8;
    uint4 w;
    w.x = (unsigned)slots[j0+0] | ((unsigned)slots[j0+1] << 16);
    w.y = (unsigned)slots[j0+2] | ((unsigned)slots[j0+3] << 16);
    w.z = (unsigned)slots[j0+4] | ((unsigned)slots[j0+5] << 16);
    w.w = (unsigned)slots[j0+6] | ((unsigned)slots[j0+7] << 16);
    unsigned short* pan = whichB ? bpan : apan;
    uint4* dst = (uint4*)pan + ((size_t)((wc * 2 + n) * NTILES + tile) * 64 + lane);
    *dst = w;
}

// Both directions as ROW-min-only kernels (dir1 = transposed product).
// Hot loop per phase: 2 loads + 4 MFMA + 2 guards + 32 min3 (0.5 instr/elem
// fold floor). Epilogue: TWO 128-row LDS transpose-merge passes (halves LDS
// to 16.9 KB -> 8-9 blocks/CU occupancy cap vs R15's 4). Grid = 2048 blocks
// = exactly 8 blocks/CU resident.
// D layout (R7/R9 HW-verified): col=lane&31, row=(r&3)+8*(r>>2)+4*(lane>>5).
__global__ __launch_bounds__(256, 4) void chamfer_rows(
    const unsigned short* __restrict__ apan, const unsigned short* __restrict__ bpan,
    unsigned int* __restrict__ mins /* [2][NBATCH][NPTS] */)
{
    __shared__ float ldsr[128 * 33];   // 16896 B, two-pass reuse

    int bid = blockIdx.x;
    const int jc  = bid & (JCH - 1); bid >>= 3;
    const int tg  = bid & (TG - 1);  bid >>= 6;
    const int n   = bid & 1;         bid >>= 1;
    const int dir = bid;             // 0: rows=c1,cols=c2 ; 1: rows=c2,cols=c1

    const int lane   = threadIdx.x & 63;
    const int wv     = threadIdx.x >> 6;
    const int colw   = lane & 31;
    const int laneHi = lane >> 5;
    const int rt0    = tg * 8 + wv * 2;     // this wave's 2 row-tiles

    const s16x8 a0 = *(const s16x8*)(
        apan + ((size_t)((dir * 2 + n) * NTILES + rt0) * 64 + lane) * 8);
    const s16x8 a1 = *(const s16x8*)(
        apan + ((size_t)((dir * 2 + n) * NTILES + rt0 + 1) * 64 + lane) * 8);
    const unsigned short* B =
        bpan + ((size_t)(((1 - dir) * 2 + n) * NTILES + jc * NT_PER) * 64 + lane) * 8;

#define LDT(t) (*(const s16x8*)(B + (size_t)(t) * 512))

    float rm0[16], rm1[16];
    #pragma unroll
    for (int r = 0; r < 16; ++r) { rm0[r] = 3.0e38f; rm1[r] = 3.0e38f; }

    s16x8 b0 = LDT(0), b1 = LDT(1), b2 = LDT(2), b3 = LDT(3);

    // PHASE consumes 2 b-tiles (bc0,bc1), prefetches tiles p0,p1 into them.
#define PHASE(bc0, bc1, p0, p1)                                               \
    {                                                                         \
        f32x16 dA = mfma32(a0, bc0);                                          \
        f32x16 dB = mfma32(a0, bc1);                                          \
        __builtin_amdgcn_sched_barrier(0);                                    \
        asm volatile("s_nop 7\n\ts_nop 7\n\ts_nop 7" :: "v"(dA), "v"(dB));    \
        __builtin_amdgcn_sched_barrier(0);                                    \
        _Pragma("unroll")                                                     \
        for (int r = 0; r < 16; ++r) min3f(rm0[r], dA[r], dB[r]);             \
        f32x16 dC = mfma32(a1, bc0);                                          \
        f32x16 dD = mfma32(a1, bc1);                                          \
        bc0 = LDT((p0) & (NT_PER - 1));                                       \
        bc1 = LDT((p1) & (NT_PER - 1));                                       \
        __builtin_amdgcn_sched_barrier(0);                                    \
        asm volatile("s_nop 7\n\ts_nop 7\n\ts_nop 7" :: "v"(dC), "v"(dD));    \
        __builtin_amdgcn_sched_barrier(0);                                    \
        _Pragma("unroll")                                                     \
        for (int r = 0; r < 16; ++r) min3f(rm1[r], dC[r], dD[r]);             \
    }

    #pragma unroll
    for (int tt = 0; tt < NT_PER / 4; ++tt) {
        PHASE(b0, b1, 4 * tt + 4, 4 * tt + 5);
        PHASE(b2, b3, 4 * tt + 6, 4 * tt + 7);
    }
#undef PHASE
#undef LDT

    // Epilogue: two 128-row transpose-merge passes through LDS.
    // Pass p covers row-tiles rt0+p of all waves: local idx = wv*32 + crow,
    // global row = tg*256 + wv*64 + p*32 + crow. Stride 33 -> bank =
    // (idx+col)%32: writes 2-way aliased (free), reads 2 lanes/bank (free).
    unsigned int* md = mins + (size_t)(dir * NBATCH + n) * NPTS + tg * 256;
    const int tid = threadIdx.x;

    #pragma unroll
    for (int p = 0; p < 2; ++p) {
        const float* rm = p ? rm1 : rm0;
        #pragma unroll
        for (int r = 0; r < 16; ++r) {
            const int cr = (r & 3) + 8 * (r >> 2) + 4 * laneHi;   // 0..31
            ldsr[(wv * 32 + cr) * 33 + colw] = rm[r];
        }
        __syncthreads();
        if (tid < 128) {
            const float* Lr = &ldsr[tid * 33];
            float c = min3v(Lr[0], Lr[1], Lr[2]);
            #pragma unroll
            for (int u = 0; u < 14; ++u) c = min3v(c, Lr[3 + 2 * u], Lr[4 + 2 * u]);
            c = fminf(c, Lr[31]);
            int rowg = (tid >> 5) * 64 + p * 32 + (tid & 31);
            atomicMin(&md[rowg], __float_as_uint(fmaxf(c, 0.0f)));
        }
        __syncthreads();
    }
}

// out[n] = mean_i min_a2b + mean_j min_b2a  (P1 == P2 so one divide).
__global__ __launch_bounds__(1024) void chamfer_out(
    const unsigned int* __restrict__ mins, float* __restrict__ out)
{
    int n = blockIdx.x;
    float acc = 0.0f;
    for (int i = threadIdx.x; i < NPTS; i += 1024) {
        acc += __uint_as_float(mins[(0 * NBATCH + n) * NPTS + i]);
        acc += __uint_as_float(mins[(1 * NBATCH + n) * NPTS + i]);
    }
    for (int off = 32; off > 0; off >>= 1) acc += __shfl_down(acc, off, 64);
    __shared__ float sm[16];
    int wv = threadIdx.x >> 6, ln = threadIdx.x & 63;
    if (ln == 0) sm[wv] = acc;
    __syncthreads();
    if (threadIdx.x == 0) {
        float tot = 0.0f;
        #pragma unroll
        for (int w = 0; w < 16; ++w) tot += sm[w];
        out[n] = tot / (float)NPTS;
    }
}

extern "C" void kernel_launch(void* const* d_in, const int* in_sizes, int n_in,
                              void* d_out, int out_size, void* d_ws, size_t ws_size,
                              hipStream_t stream)
{
    const float* c1 = (const float*)d_in[0];
    const float* c2 = (const float*)d_in[1];
    float* out = (float*)d_out;

    char* ws = (char*)d_ws;
    // mins at base: 256 KiB. apan 2 MiB (both clouds), bpan 2 MiB.
    // Total 4.4375 MiB (R7-proven footprint).
    unsigned int*   mins = (unsigned int*)ws;
    unsigned short* apan = (unsigned short*)(ws + (size_t)(2 * NBATCH * NPTS) * 4);
    unsigned short* bpan = apan + (size_t)2 * NBATCH * NTILES * 512;

    pack_panels<<<(1 << 18) / 256, 256, 0, stream>>>(c1, c2, apan, bpan, mins);
    chamfer_rows<<<2 * NBATCH * TG * JCH, 256, 0, stream>>>(apan, bpan, mins);
    chamfer_out<<<NBATCH, 1024, 0, stream>>>(mins, out);
}

// Round 17
// 50.547 us; speedup vs baseline: 1.0316x; 1.0316x over previous
//
#include <hip/hip_runtime.h>

#define NBATCH 2
#define NPTS   16384
#define TPTS   32                      // points per MFMA tile (32x32x16)
#define NTILES (NPTS / TPTS)           // 512
#define JCH    8                       // col-chunks per (dir,n): 2048 cols each
#define NT_PER (NTILES / JCH)          // 64 col-tiles per chunk
#define NQUAD  (NT_PER / 4)            // 16 quads (4 tiles each)
#define TG     (NPTS / 256)            // 64 row-groups (block = 4 waves x 64 rows)

typedef float f32x16 __attribute__((ext_vector_type(16)));
typedef short s16x8  __attribute__((ext_vector_type(8)));

__device__ __forceinline__ unsigned short f2bf(float f) {   // RTNE, finite inputs
    unsigned u = __float_as_uint(f);
    u += 0x7FFF + ((u >> 16) & 1);
    return (unsigned short)(u >> 16);
}
__device__ __forceinline__ float bf2f(unsigned short h) {
    return __uint_as_float((unsigned)h << 16);
}

// Inline-asm MFMA: VGPR destination (no ACC-class tax), literal-0 C.
__device__ __forceinline__ f32x16 mfma32(s16x8 a, s16x8 b) {
    f32x16 d;
    asm volatile("v_mfma_f32_32x32x16_bf16 %0, %1, %2, 0"
                 : "=&v"(d) : "v"(a), "v"(b));
    return d;
}
__device__ __forceinline__ void min3f(float& acc, float x, float y) {
    asm("v_min3_f32 %0, %1, %2, %3" : "=v"(acc) : "v"(acc), "v"(x), "v"(y));
}
__device__ __forceinline__ float min3v(float x, float y, float z) {
    float r;
    asm("v_min3_f32 %0, %1, %2, %3" : "=v"(r) : "v"(x), "v"(y), "v"(z));
    return r;
}

// K=16 panels: BOTH clouds in BOTH encodings (R11-proven slot layout).
// A slots: [ah(3) | al(3) | ah(3) | 1 1 | sqa_h sqa_l | 0 0 0]
// B slots: [-2bh(3)| -2bh(3)| -2bl(3)| sqb_h sqb_l | 1 1 | 0 0 0]
// dot = sqa + sqb - 2(ah+al)·bh - 2ah·bl = d^2 + eps, |eps| <~ 1.3e-4 worst.
// Also initializes the mins arrays (fused memset).
__global__ __launch_bounds__(256) void pack_panels(
    const float* __restrict__ c1, const float* __restrict__ c2,
    unsigned short* __restrict__ apan, unsigned short* __restrict__ bpan,
    unsigned int* __restrict__ mins)
{
    int tid = blockIdx.x * 256 + threadIdx.x;   // 2^18 threads
    if (tid < 2 * NBATCH * NPTS) mins[tid] = 0x7F7F7F7Fu;   // fused init

    int lane   = tid & 63;
    int tile   = (tid >> 6) & (NTILES - 1);
    int n      = (tid >> 15) & 1;
    int whichB = (tid >> 16) & 1;
    int wc     = (tid >> 17) & 1;               // which cloud

    const float* src = wc ? c2 : c1;

    int p = tile * TPTS + (lane & 31);
    const float* q = src + ((size_t)n * NPTS + p) * 3;
    float x = q[0], y = q[1], z = q[2];

    unsigned short xh = f2bf(x), yh = f2bf(y), zh = f2bf(z);
    unsigned short xl = f2bf(x - bf2f(xh)), yl = f2bf(y - bf2f(yh)), zl = f2bf(z - bf2f(zh));
    float sq = x * x + y * y + z * z;
    unsigned short sh = f2bf(sq);
    unsigned short sl = f2bf(sq - bf2f(sh));
    const unsigned short one = 0x3F80;

    unsigned short slots[16];
    if (!whichB) {
        slots[0]=xh;  slots[1]=yh;  slots[2]=zh;
        slots[3]=xl;  slots[4]=yl;  slots[5]=zl;
        slots[6]=xh;  slots[7]=yh;  slots[8]=zh;
        slots[9]=one; slots[10]=one;
        slots[11]=sh; slots[12]=sl;
        slots[13]=0;  slots[14]=0;  slots[15]=0;
    } else {
        unsigned short mxh=f2bf(-2.f*bf2f(xh)), myh=f2bf(-2.f*bf2f(yh)), mzh=f2bf(-2.f*bf2f(zh));
        unsigned short mxl=f2bf(-2.f*bf2f(xl)), myl=f2bf(-2.f*bf2f(yl)), mzl=f2bf(-2.f*bf2f(zl));
        slots[0]=mxh; slots[1]=myh; slots[2]=mzh;
        slots[3]=mxh; slots[4]=myh; slots[5]=mzh;
        slots[6]=mxl; slots[7]=myl; slots[8]=mzl;
        slots[9]=sh;  slots[10]=sl;
        slots[11]=one; slots[12]=one;
        slots[13]=0;  slots[14]=0;  slots[15]=0;
    }

    int j0 = (lane >> 5) * 8;
    uint4 w;
    w.x = (unsigned)slots[j0+0] | ((unsigned)slots[j0+1] << 16);
    w.y = (unsigned)slots[j0+2] | ((unsigned)slots[j0+3] << 16);
    w.z = (unsigned)slots[j0+4] | ((unsigned)slots[j0+5] << 16);
    w.w = (unsigned)slots[j0+6] | ((unsigned)slots[j0+7] << 16);
    unsigned short* pan = whichB ? bpan : apan;
    uint4* dst = (uint4*)pan + ((size_t)((wc * 2 + n) * NTILES + tile) * 64 + lane);
    *dst = w;
}

// Row-only kernel (both directions via grid), now with BLOCK-COOPERATIVE
// double-buffered LDS staging of the shared B stream (R13->R14 lesson:
// 4 waves re-reading the same tiles through L1 = 4x redundant + latency
// stalls). Per quad: each wave global-loads ONE tile early (T14 issue-early/
// write-late), processes 4 tiles from LDS, then ds_writes its prefetched
// tile to the alternate buffer; __syncthreads per quad is ~free (counters
// already drained by data deps). Staging LDS aliases the epilogue buffer.
// D layout (R7/R9 HW-verified): col=lane&31, row=(r&3)+8*(r>>2)+4*(lane>>5).
__global__ __launch_bounds__(256, 4) void chamfer_rows(
    const unsigned short* __restrict__ apan, const unsigned short* __restrict__ bpan,
    unsigned int* __restrict__ mins /* [2][NBATCH][NPTS] */)
{
    __shared__ float ldsr[128 * 33];        // 16896 B epilogue buffer
    short* bst = (short*)ldsr;              // first 8 KB: B stage [2][4][512]

    int bid = blockIdx.x;
    const int jc  = bid & (JCH - 1); bid >>= 3;
    const int tg  = bid & (TG - 1);  bid >>= 6;
    const int n   = bid & 1;         bid >>= 1;
    const int dir = bid;             // 0: rows=c1,cols=c2 ; 1: rows=c2,cols=c1

    const int lane   = threadIdx.x & 63;
    const int wv     = threadIdx.x >> 6;
    const int colw   = lane & 31;
    const int laneHi = lane >> 5;
    const int rt0    = tg * 8 + wv * 2;     // this wave's 2 row-tiles

    const s16x8 a0 = *(const s16x8*)(
        apan + ((size_t)((dir * 2 + n) * NTILES + rt0) * 64 + lane) * 8);
    const s16x8 a1 = *(const s16x8*)(
        apan + ((size_t)((dir * 2 + n) * NTILES + rt0 + 1) * 64 + lane) * 8);
    const unsigned short* B =
        bpan + ((size_t)(((1 - dir) * 2 + n) * NTILES + jc * NT_PER) * 64 + lane) * 8;

    float rm0[16], rm1[16];
    #pragma unroll
    for (int r = 0; r < 16; ++r) { rm0[r] = 3.0e38f; rm1[r] = 3.0e38f; }

    // MFMA -> fold with hazard guard (rule #18 fence pattern, R11-proven)
#define DUOF(aa, rmv, tt0, tt1)                                               \
    {                                                                         \
        f32x16 dX = mfma32(aa, tt0);                                          \
        f32x16 dY = mfma32(aa, tt1);                                          \
        __builtin_amdgcn_sched_barrier(0);                                    \
        asm volatile("s_nop 7\n\ts_nop 7\n\ts_nop 7" :: "v"(dX), "v"(dY));    \
        __builtin_amdgcn_sched_barrier(0);                                    \
        _Pragma("unroll")                                                     \
        for (int r = 0; r < 16; ++r) min3f(rmv[r], dX[r], dY[r]);             \
    }

    // prologue: stage quad 0 into buffer 0 (wave wv owns tile wv of the quad)
    {
        s16x8 g0 = *(const s16x8*)(B + (size_t)wv * 512);
        *(s16x8*)(bst + wv * 512 + lane * 8) = g0;
    }

    #pragma unroll 2
    for (int q = 0; q < NQUAD; ++q) {
        const int b = q & 1;
        __syncthreads();   // quad q visible; all reads of buf b^1 retired

        // T14 issue-early: next quad's tile slice -> registers (wraps at tail)
        const int nq = (q + 1) & (NQUAD - 1);
        const s16x8 g = *(const s16x8*)(B + (size_t)(nq * 4 + wv) * 512);

        // process quad q from LDS (all 4 ds_reads up front: one latency hit)
        const short* tb = bst + b * 2048 + lane * 8;
        s16x8 t0 = *(const s16x8*)(tb);
        s16x8 t1 = *(const s16x8*)(tb + 512);
        s16x8 t2 = *(const s16x8*)(tb + 1024);
        s16x8 t3 = *(const s16x8*)(tb + 1536);
        DUOF(a0, rm0, t0, t1);
        DUOF(a1, rm1, t0, t1);
        DUOF(a0, rm0, t2, t3);
        DUOF(a1, rm1, t2, t3);

        // T14 write-late: park the prefetched tile in the alternate buffer
        *(s16x8*)(bst + (b ^ 1) * 2048 + wv * 512 + lane * 8) = g;
    }
#undef DUOF

    __syncthreads();   // staging area done; safe to reuse ldsr for epilogue

    // Epilogue: two 128-row transpose-merge passes through LDS (stride 33:
    // writes 2-way bank-aliased = free, reads 2 lanes/bank = free).
    unsigned int* md = mins + (size_t)(dir * NBATCH + n) * NPTS + tg * 256;
    const int tid = threadIdx.x;

    #pragma unroll
    for (int p = 0; p < 2; ++p) {
        const float* rm = p ? rm1 : rm0;
        #pragma unroll
        for (int r = 0; r < 16; ++r) {
            const int cr = (r & 3) + 8 * (r >> 2) + 4 * laneHi;   // 0..31
            ldsr[(wv * 32 + cr) * 33 + colw] = rm[r];
        }
        __syncthreads();
        if (tid < 128) {
            const float* Lr = &ldsr[tid * 33];
            float c = min3v(Lr[0], Lr[1], Lr[2]);
            #pragma unroll
            for (int u = 0; u < 14; ++u) c = min3v(c, Lr[3 + 2 * u], Lr[4 + 2 * u]);
            c = fminf(c, Lr[31]);
            int rowg = (tid >> 5) * 64 + p * 32 + (tid & 31);
            atomicMin(&md[rowg], __float_as_uint(fmaxf(c, 0.0f)));
        }
        __syncthreads();
    }
}

// out[n] = mean_i min_a2b + mean_j min_b2a  (P1 == P2 so one divide).
__global__ __launch_bounds__(1024) void chamfer_out(
    const unsigned int* __restrict__ mins, float* __restrict__ out)
{
    int n = blockIdx.x;
    float acc = 0.0f;
    for (int i = threadIdx.x; i < NPTS; i += 1024) {
        acc += __uint_as_float(mins[(0 * NBATCH + n) * NPTS + i]);
        acc += __uint_as_float(mins[(1 * NBATCH + n) * NPTS + i]);
    }
    for (int off = 32; off > 0; off >>= 1) acc += __shfl_down(acc, off, 64);
    __shared__ float sm[16];
    int wv = threadIdx.x >> 6, ln = threadIdx.x & 63;
    if (ln == 0) sm[wv] = acc;
    __syncthreads();
    if (threadIdx.x == 0) {
        float tot = 0.0f;
        #pragma unroll
        for (int w = 0; w < 16; ++w) tot += sm[w];
        out[n] = tot / (float)NPTS;
    }
}

extern "C" void kernel_launch(void* const* d_in, const int* in_sizes, int n_in,
                              void* d_out, int out_size, void* d_ws, size_t ws_size,
                              hipStream_t stream)
{
    const float* c1 = (const float*)d_in[0];
    const float* c2 = (const float*)d_in[1];
    float* out = (float*)d_out;

    char* ws = (char*)d_ws;
    // mins at base: 256 KiB. apan 2 MiB (both clouds), bpan 2 MiB.
    // Total 4.4375 MiB (R7-proven footprint).
    unsigned int*   mins = (unsigned int*)ws;
    unsigned short* apan = (unsigned short*)(ws + (size_t)(2 * NBATCH * NPTS) * 4);
    unsigned short* bpan = apan + (size_t)2 * NBATCH * NTILES * 512;

    pack_panels<<<(1 << 18) / 256, 256, 0, stream>>>(c1, c2, apan, bpan, mins);
    chamfer_rows<<<2 * NBATCH * TG * JCH, 256, 0, stream>>>(apan, bpan, mins);
    chamfer_out<<<NBATCH, 1024, 0, stream>>>(mins, out);
}

// Round 18
// 46.624 us; speedup vs baseline: 1.1185x; 1.0842x over previous
//
#include <hip/hip_runtime.h>

#define NBATCH 2
#define NPTS   16384
#define TPTS   32                      // points per MFMA tile (32x32x16)
#define NTILES (NPTS / TPTS)           // 512
#define JCH    16                      // col-chunks per batch: 1024 cols each
#define NT_PER (NTILES / JCH)          // 32 col-tiles per chunk
#define TG     (NPTS / 128)            // 128 row-groups (block = 4 waves x 32 rows)

typedef float f32x16 __attribute__((ext_vector_type(16)));
typedef short s16x8  __attribute__((ext_vector_type(8)));

__device__ __forceinline__ unsigned short f2bf(float f) {   // RTNE, finite inputs
    unsigned u = __float_as_uint(f);
    u += 0x7FFF + ((u >> 16) & 1);
    return (unsigned short)(u >> 16);
}
__device__ __forceinline__ float bf2f(unsigned short h) {
    return __uint_as_float((unsigned)h << 16);
}
__device__ __forceinline__ unsigned umin2(unsigned a, unsigned b) { return a < b ? a : b; }

// Inline-asm MFMA: VGPR destination (no ACC-class tax), literal-0 C.
__device__ __forceinline__ f32x16 mfma32(s16x8 a, s16x8 b) {
    f32x16 d;
    asm volatile("v_mfma_f32_32x32x16_bf16 %0, %1, %2, 0"
                 : "=&v"(d) : "v"(a), "v"(b));
    return d;
}
__device__ __forceinline__ void min3f(float& acc, float x, float y) {
    asm("v_min3_f32 %0, %1, %2, %3" : "=v"(acc) : "v"(acc), "v"(x), "v"(y));
}
__device__ __forceinline__ float min3v(float x, float y, float z) {
    float r;
    asm("v_min3_f32 %0, %1, %2, %3" : "=v"(r) : "v"(x), "v"(y), "v"(z));
    return r;
}
__device__ __forceinline__ float tree16(const f32x16& d) {  // min of 16 regs, 8 instrs
    float c = min3v(d[0], d[1], d[2]);
    c = min3v(c, d[3],  d[4]);  c = min3v(c, d[5],  d[6]);
    c = min3v(c, d[7],  d[8]);  c = min3v(c, d[9],  d[10]);
    c = min3v(c, d[11], d[12]); c = min3v(c, d[13], d[14]);
    return fminf(c, d[15]);
}

// K=16 panels, ONE matrix per n: rows = cloud1 (A-side), cols = cloud2 (B-side).
// A slots: [ah(3) | al(3) | ah(3) | 1 1 | sqa_h sqa_l | 0 0 0]
// B slots: [-2bh(3)| -2bh(3)| -2bl(3)| sqb_h sqb_l | 1 1 | 0 0 0]
// dot = sqa + sqb - 2(ah+al)·bh - 2ah·bl = d^2 + eps, |eps| <~ 1.3e-4 worst.
// Also initializes the mins arrays (fused memset).
__global__ __launch_bounds__(256) void pack_panels(
    const float* __restrict__ c1, const float* __restrict__ c2,
    unsigned short* __restrict__ apan, unsigned short* __restrict__ bpan,
    unsigned int* __restrict__ mins)
{
    int tid = blockIdx.x * 256 + threadIdx.x;   // 2^17 threads
    if (tid < 2 * NBATCH * NPTS) mins[tid] = 0x7F7F7F7Fu;   // fused init

    int lane   = tid & 63;
    int tile   = (tid >> 6) & (NTILES - 1);
    int n      = (tid >> 15) & 1;
    int whichB = (tid >> 16) & 1;

    const float* src = whichB ? c2 : c1;

    int p = tile * TPTS + (lane & 31);
    const float* q = src + ((size_t)n * NPTS + p) * 3;
    float x = q[0], y = q[1], z = q[2];

    unsigned short xh = f2bf(x), yh = f2bf(y), zh = f2bf(z);
    unsigned short xl = f2bf(x - bf2f(xh)), yl = f2bf(y - bf2f(yh)), zl = f2bf(z - bf2f(zh));
    float sq = x * x + y * y + z * z;
    unsigned short sh = f2bf(sq);
    unsigned short sl = f2bf(sq - bf2f(sh));
    const unsigned short one = 0x3F80;

    unsigned short slots[16];
    if (!whichB) {
        slots[0]=xh;  slots[1]=yh;  slots[2]=zh;
        slots[3]=xl;  slots[4]=yl;  slots[5]=zl;
        slots[6]=xh;  slots[7]=yh;  slots[8]=zh;
        slots[9]=one; slots[10]=one;
        slots[11]=sh; slots[12]=sl;
        slots[13]=0;  slots[14]=0;  slots[15]=0;
    } else {
        unsigned short mxh=f2bf(-2.f*bf2f(xh)), myh=f2bf(-2.f*bf2f(yh)), mzh=f2bf(-2.f*bf2f(zh));
        unsigned short mxl=f2bf(-2.f*bf2f(xl)), myl=f2bf(-2.f*bf2f(yl)), mzl=f2bf(-2.f*bf2f(zl));
        slots[0]=mxh; slots[1]=myh; slots[2]=mzh;
        slots[3]=mxh; slots[4]=myh; slots[5]=mzh;
        slots[6]=mxl; slots[7]=myl; slots[8]=mzl;
        slots[9]=sh;  slots[10]=sl;
        slots[11]=one; slots[12]=one;
        slots[13]=0;  slots[14]=0;  slots[15]=0;
    }

    int j0 = (lane >> 5) * 8;
    uint4 w;
    w.x = (unsigned)slots[j0+0] | ((unsigned)slots[j0+1] << 16);
    w.y = (unsigned)slots[j0+2] | ((unsigned)slots[j0+3] << 16);
    w.z = (unsigned)slots[j0+4] | ((unsigned)slots[j0+5] << 16);
    w.w = (unsigned)slots[j0+6] | ((unsigned)slots[j0+7] << 16);
    unsigned short* pan = whichB ? bpan : apan;
    uint4* dst = (uint4*)pan + ((size_t)(n * NTILES + tile) * 64 + lane);
    *dst = w;
}

// ONE pass over each d^2 matrix -> BOTH reductions (halves MFMA count and
// panel traffic vs the R15-R17 two-matrix design). Lean R15 skeleton:
// asm MFMA + guard, explicit 4-reg ring, no in-loop movs. Col side per tile:
// tree16 (8 min3) + shfl_xor(32) + plain store to a per-wave LDS slice
// (R9/R11-proven race-free; both half-lanes store the same value). Epilogue:
// col merge (4 slices) then row transpose-merge, sharing one LDS buffer.
// T5 setprio(1) around the MFMA pair.
// D layout (R7/R9 HW-verified): col=lane&31, row=(r&3)+8*(r>>2)+4*(lane>>5).
__global__ __launch_bounds__(256, 4) void chamfer_mm(
    const unsigned short* __restrict__ apan, const unsigned short* __restrict__ bpan,
    unsigned int* __restrict__ rowmins, unsigned int* __restrict__ colmins)
{
    __shared__ float ldsr[128 * 33];                      // 16896 B, dual-use
    unsigned int (*lcol)[NT_PER * 32] =
        (unsigned int (*)[NT_PER * 32])ldsr;              // [4][1024] col slices

    int bid = blockIdx.x;
    const int jc = bid & (JCH - 1); bid >>= 4;
    const int tg = bid & (TG - 1);  bid >>= 7;
    const int n  = bid;

    const int lane   = threadIdx.x & 63;
    const int wv     = threadIdx.x >> 6;
    const int colw   = lane & 31;
    const int laneHi = lane >> 5;
    const int mt     = tg * 4 + wv;      // this wave's a-tile (32 rows)

    const s16x8 a = *(const s16x8*)(
        apan + ((size_t)(n * NTILES + mt) * 64 + lane) * 8);
    const unsigned short* B =
        bpan + ((size_t)(n * NTILES + jc * NT_PER) * 64 + lane) * 8;

#define LDT(t) (*(const s16x8*)(B + (size_t)(t) * 512))

    float rm[16];
    #pragma unroll
    for (int r = 0; r < 16; ++r) rm[r] = 3.0e38f;

    s16x8 b0 = LDT(0), b1 = LDT(1), b2 = LDT(2), b3 = LDT(3);

    // PHASE: 2 MFMA on (bc0,bc1) -> prefetch p0,p1 into them -> guard ->
    // 16 row-min3 + 2 col tree16 + shfl + LDS store (tiles t0,t1).
#define PHASE(bc0, bc1, t0, t1, p0, p1)                                       \
    {                                                                         \
        __builtin_amdgcn_s_setprio(1);                                        \
        f32x16 dX = mfma32(a, bc0);                                           \
        f32x16 dY = mfma32(a, bc1);                                           \
        __builtin_amdgcn_s_setprio(0);                                        \
        bc0 = LDT((p0) & (NT_PER - 1));                                       \
        bc1 = LDT((p1) & (NT_PER - 1));                                       \
        __builtin_amdgcn_sched_barrier(0);                                    \
        asm volatile("s_nop 7\n\ts_nop 7\n\ts_nop 7" :: "v"(dX), "v"(dY));    \
        __builtin_amdgcn_sched_barrier(0);                                    \
        _Pragma("unroll")                                                     \
        for (int r = 0; r < 16; ++r) min3f(rm[r], dX[r], dY[r]);              \
        float c0 = tree16(dX), c1 = tree16(dY);                               \
        c0 = fminf(c0, __shfl_xor(c0, 32, 64));                               \
        c1 = fminf(c1, __shfl_xor(c1, 32, 64));                               \
        lcol[wv][(t0) * 32 + colw] = __float_as_uint(fmaxf(c0, 0.f));         \
        lcol[wv][(t1) * 32 + colw] = __float_as_uint(fmaxf(c1, 0.f));         \
    }

    #pragma unroll
    for (int tt = 0; tt < NT_PER / 4; ++tt) {
        PHASE(b0, b1, 4 * tt,     4 * tt + 1, 4 * tt + 4, 4 * tt + 5);
        PHASE(b2, b3, 4 * tt + 2, 4 * tt + 3, 4 * tt + 6, 4 * tt + 7);
    }
#undef PHASE
#undef LDT

    // ---- epilogue 1: col merge (4 slices -> global), 4 slots/thread ----
    __syncthreads();
    unsigned int* cbase = colmins + (size_t)n * NPTS + jc * (NT_PER * 32);
    #pragma unroll
    for (int u = 0; u < (NT_PER * 32) / 256; ++u) {
        int s = u * 256 + threadIdx.x;
        unsigned int k = umin2(umin2(lcol[0][s], lcol[1][s]),
                               umin2(lcol[2][s], lcol[3][s]));
        atomicMin(&cbase[s], k);
    }
    __syncthreads();   // col slices dead; reuse ldsr for row transpose

    // ---- epilogue 2: row transpose-merge (stride 33: 2-way aliasing free) --
    #pragma unroll
    for (int r = 0; r < 16; ++r) {
        const int cr = (r & 3) + 8 * (r >> 2) + 4 * laneHi;   // 0..31
        ldsr[(wv * 32 + cr) * 33 + colw] = rm[r];
    }
    __syncthreads();
    const int tid = threadIdx.x;
    if (tid < 128) {
        const float* Lr = &ldsr[tid * 33];
        float c = min3v(Lr[0], Lr[1], Lr[2]);
        #pragma unroll
        for (int u = 0; u < 14; ++u) c = min3v(c, Lr[3 + 2 * u], Lr[4 + 2 * u]);
        c = fminf(c, Lr[31]);
        atomicMin(&rowmins[(size_t)n * NPTS + tg * 128 + tid],
                  __float_as_uint(fmaxf(c, 0.0f)));
    }
}

// out[n] = mean_i min_a2b + mean_j min_b2a  (P1 == P2 so one divide).
__global__ __launch_bounds__(1024) void chamfer_out(
    const unsigned int* __restrict__ mins, float* __restrict__ out)
{
    int n = blockIdx.x;
    float acc = 0.0f;
    for (int i = threadIdx.x; i < NPTS; i += 1024) {
        acc += __uint_as_float(mins[(0 * NBATCH + n) * NPTS + i]);
        acc += __uint_as_float(mins[(1 * NBATCH + n) * NPTS + i]);
    }
    for (int off = 32; off > 0; off >>= 1) acc += __shfl_down(acc, off, 64);
    __shared__ float sm[16];
    int wv = threadIdx.x >> 6, ln = threadIdx.x & 63;
    if (ln == 0) sm[wv] = acc;
    __syncthreads();
    if (threadIdx.x == 0) {
        float tot = 0.0f;
        #pragma unroll
        for (int w = 0; w < 16; ++w) tot += sm[w];
        out[n] = tot / (float)NPTS;
    }
}

extern "C" void kernel_launch(void* const* d_in, const int* in_sizes, int n_in,
                              void* d_out, int out_size, void* d_ws, size_t ws_size,
                              hipStream_t stream)
{
    const float* c1 = (const float*)d_in[0];
    const float* c2 = (const float*)d_in[1];
    float* out = (float*)d_out;

    char* ws = (char*)d_ws;
    // mins at base: 256 KiB. apan 1 MiB, bpan 1 MiB. Total 2.25 MiB (R11-proven).
    unsigned int*   mins = (unsigned int*)ws;
    unsigned short* apan = (unsigned short*)(ws + (size_t)(2 * NBATCH * NPTS) * 4);
    unsigned short* bpan = apan + (size_t)NBATCH * NTILES * 512;

    unsigned int* rowmins = mins;                          // cloud1 -> cloud2
    unsigned int* colmins = mins + (size_t)NBATCH * NPTS;  // cloud2 -> cloud1

    pack_panels<<<(1 << 17) / 256, 256, 0, stream>>>(c1, c2, apan, bpan, mins);
    chamfer_mm<<<NBATCH * TG * JCH, 256, 0, stream>>>(apan, bpan, rowmins, colmins);
    chamfer_out<<<NBATCH, 1024, 0, stream>>>(mins, out);
}